// Round 6
// baseline (73.285 us; speedup 1.0000x reference)
//
#include <hip/hip_runtime.h>
#include <math.h>

// HorizonReward: 60-step UT cartpole rollout, single wave, zero LDS.
// R6: instruction-count cut — one-hot fma masks replace cndmask select
// chains; v_pk_fma_f32 packed math on all pair-parallel dataflow.
// Structure (from R5): dynamics affine in u (thacc=g0+g1u) so all
// reductions except v1/v3 covariance run before u; f32 throughout except
// the angle accumulator rev (f64). Row replication: roles keyed on
// (lane&15); 4 identical rows let each row reduce a different quantity.

typedef float v2f __attribute__((ext_vector_type(2)));

template <int CTRL>
__device__ __forceinline__ float dpp_add_f(float v) {
    int s = __builtin_amdgcn_update_dpp(0, __float_as_int(v), CTRL, 0xF, 0xF, true);
    return v + __int_as_float(s);
}
// sum within each 16-lane row: quad_perm[1,0,3,2], quad_perm[2,3,0,1],
// row_ror:4, row_ror:8
__device__ __forceinline__ float row_sum_f(float v) {
    v = dpp_add_f<0xB1>(v);
    v = dpp_add_f<0x4E>(v);
    v = dpp_add_f<0x124>(v);
    v = dpp_add_f<0x128>(v);
    return v;
}
__device__ __forceinline__ float rl(float v, int lane) {
    return __int_as_float(__builtin_amdgcn_readlane(__float_as_int(v), lane));
}
// full 64-lane sum -> lane63 via row_bcast15 / row_bcast31
__device__ __forceinline__ float wave_sum_f(float v) {
    v = row_sum_f(v);
    v = dpp_add_f<0x142>(v);
    v = dpp_add_f<0x143>(v);
    return rl(v, 63);
}

__global__ __launch_bounds__(64) void horizon_kernel(const float* __restrict__ p,
                                                     float* __restrict__ out) {
    const int l   = threadIdx.x;
    const int l15 = l & 15;
    const int row = l >> 4;

    const float SQL2E  = 1.2011224087864498f;    // sqrt(log2 e)
    const float INV_MT = 0.9090909090909091f;    // 1/1.1
    const float KCS    = -0.045454545454545456f; // -0.05/1.1
    const double INV2PI_D = 0.15915494309189535;
    const float  INV2PI_F = 0.15915494309189535f;
    const float DIAG5  = 0.00251f;               // 5*(PN*DT + 2*JITTER)

    // per-lane RBF params, pre-scaled so exp(-qn) = exp2(-(qn*log2e)),
    // packed into v2f pairs for the pk-fma policy dot products.
    float w = 0.0f, mu0 = 0.0f, mu1 = 0.0f, mu2 = 0.0f, mu3 = 0.0f;
    v2f S0 = {0,0}, S1 = {0,0}, S2 = {0,0}, S3 = {0,0};  // for (t0,t1)
    v2f T2 = {0,0}, T3 = {0,0};                          // for (t2,t3)
    if (l < 50) {
        w   = p[l];
        mu0 = p[ 50 + l]; mu1 = p[100 + l]; mu2 = p[150 + l]; mu3 = p[200 + l];
        const float* q = p + 250 + 10 * l;
        float s0 = q[0]*SQL2E, s1 = q[1]*SQL2E, s2 = q[2]*SQL2E, s3 = q[3]*SQL2E;
        float s4 = q[4]*SQL2E, s5 = q[5]*SQL2E, s6 = q[6]*SQL2E, s7 = q[7]*SQL2E;
        float s8 = q[8]*SQL2E, s9 = q[9]*SQL2E;
        S0 = (v2f){s0, 0.f}; S1 = (v2f){s4, s1};
        S2 = (v2f){s5, s6};  S3 = (v2f){s7, s8};
        T2 = (v2f){s2, 0.f}; T3 = (v2f){s9, s3};
    }

    // sigma-point role from (l&15)
    const float wlf  = (l15 == 0) ? 0.2f : ((l15 < 9) ? 0.1f : 0.0f);
    const float fw5  = 5.0f * wlf;
    const float osgn = (l15 >= 1 && l15 <= 4) ? 1.0f
                     : ((l15 >= 5 && l15 <= 8) ? -1.0f : 0.0f);
    const int   ocol = ((l15 >= 5 ? l15 - 5 : l15 - 1) & 3);

    // one-hot fma masks (replace cndmask select chains)
    const float e0 = (ocol == 0) ? osgn : 0.0f;
    const float e1 = (ocol == 1) ? osgn : 0.0f;
    const float e2 = (ocol == 2) ? osgn : 0.0f;
    const float e3 = (ocol == 3) ? osgn : 0.0f;
    const float rA0 = (row == 0) ? wlf : 0.0f;
    const float rA1 = (row == 1) ? wlf : 0.0f;
    const float rA2 = (row == 2) ? wlf : 0.0f;
    const float rA3 = (row == 3) ? wlf : 0.0f;
    const float q0 = (row == 0) ? fw5 : 0.0f;
    const float q1 = (row == 1) ? fw5 : 0.0f;
    const float q2 = (row == 2) ? fw5 : 0.0f;
    const float q3 = (row == 3) ? fw5 : 0.0f;

    // carried state (f32 except angle accumulator rev)
    float mmf0 = 0.0f, mmf1 = 0.0f, mmf2 = 0.1f, mmf3 = 0.0f;
    float d0 = -mu0, d1 = -mu1, d2 = 0.1f - mu2, d3 = -mu3;
    double rev = 0.1 * INV2PI_D;
    float frmf = (float)rev;
    const float CI = 2.2360679774997896e-3f;     // sqrt5 * chol(JITTER*I)
    float c00=CI, c10=0.f, c20=0.f, c30=0.f;
    float c11=CI, c21=0.f, c31=0.f;
    float c22=CI, c32=0.f;
    float c33=CI;
    float acc = 0.0f;

    #pragma unroll 2
    for (int t = 0; t < 60; ++t) {
        // ---- sigma offsets via one-hot fma (column ocol of scaled chol)
        float oo0 = e0 * c00;
        float oo1 = fmaf(e0, c10, e1 * c11);
        float oo2 = fmaf(e0, c20, fmaf(e1, c21, e2 * c22));
        float oo3 = fmaf(e0, c30, fmaf(e1, c31, fmaf(e2, c32, e3 * c33)));

        float x1 = mmf1 + oo1;
        float x3 = mmf3 + oo3;

        // ---- dynamics coefficients, affine in u: thacc=g0+g1u, xacc=h0+h1u
        float rv = __builtin_amdgcn_fractf(fmaf(oo2, INV2PI_F, frmf));
        float sn = __builtin_amdgcn_sinf(rv);
        float cs = __builtin_amdgcn_cosf(rv);
        float a   = (0.045454545454545456f * (x3 * x3)) * sn;
        float den = fmaf(cs * cs, KCS, 0.6666666666666666f);
        float rden = __builtin_amdgcn_rcpf(den);
        float kcs = KCS * cs;
        v2f NUM = { fmaf(9.8f, sn, -(cs * a)), (-INV_MT) * cs };
        v2f G = NUM * rden;                      // (g0, g1)
        v2f H = { a, INV_MT };
        H = G * kcs + H;                         // (h0, h1)
        v2f HG0 = { H.x, G.x };
        v2f HG1 = { H.y, G.y };
        v2f OO13 = { oo1, oo3 };
        v2f AL = HG0 * 0.05f + OO13;             // (al1, al3)
        v2f BE = HG1 * 0.05f;                    // (be1, be3)
        v2f X13 = { x1, x3 };
        v2f OO02 = { oo0, oo2 };
        v2f DL = X13 * 0.05f + OO02;             // (dl0, dl2)

        // ---- pre-u reductions: rows reduce {dl0, al1, dl2, al3} / {_,be1,_,be3}
        float PA = row_sum_f(fmaf(rA0, DL.x, fmaf(rA1, AL.x,
                             fmaf(rA2, DL.y, rA3 * AL.y))));
        float PB = row_sum_f(fmaf(rA1, BE.x, rA3 * BE.y));
        float A0 = rl(PA, 0), A1 = rl(PA, 16), A2 = rl(PA, 32), A3 = rl(PA, 48);
        float B1 = rl(PB, 16), B3 = rl(PB, 48);

        // ---- u-free covariance pieces
        float v0 = DL.x - A0, v2v = DL.y - A2;
        float va1 = AL.x - A1, va3 = AL.y - A3;
        float vb1 = BE.x - B1, vb3 = BE.y - B3;
        // P1 rows: {v0v0, v2v0, v2v2, 0}
        float P1 = row_sum_f(fmaf(q0, v0 * v0,
                             fmaf(q1, v2v * v0, q2 * (v2v * v2v))));
        float A00 = rl(P1, 0) + DIAG5, A20 = rl(P1, 16), A22 = rl(P1, 32) + DIAG5;
        float i0 = __builtin_amdgcn_rsqf(A00);
        float nc00 = A00 * i0;
        float nc20 = A20 * i0;
        float b22p = fmaf(-nc20, nc20, A22);

        // mean components 0,2 (u-free)
        float nmm0 = mmf0 + A0, nmm2 = mmf2 + A2;
        double revn = fma((double)A2, INV2PI_D, rev);
        rev = revn - floor(revn);
        float nfrm = (float)rev;

        // ---- policy (pk dot products), uses d from previous iteration
        v2f T01 = S0 * d0 + S1 * d1;
        T01 = S2 * d2 + T01;
        T01 = S3 * d3 + T01;                     // (t0, t1)
        v2f T23 = T2 * d2 + T3 * d3;             // (t2, t3)
        v2f QQ = T01 * T01;
        QQ = T23 * T23 + QQ;
        float qn = QQ.x + QQ.y;
        float val = wave_sum_f(w * __builtin_amdgcn_exp2f(-qn));
        float u = fminf(10.0f, fmaxf(-10.0f, val));

        // ---- post-u tail
        float rd1 = fmaf(B1, u, A1);
        float rd3 = fmaf(B3, u, A3);
        d0 += A0; d2 += A2; d1 += rd1; d3 += rd3;
        float nmm1 = mmf1 + rd1, nmm3 = mmf3 + rd3;

        float v1 = fmaf(vb1, u, va1);
        float v3 = fmaf(vb3, u, va3);
        // P2 rows: {v1v0, v1v1, v1v2, v1v3}
        float P2 = row_sum_f(v1 * fmaf(q0, v0, fmaf(q1, v1,
                                  fmaf(q2, v2v, q3 * v3))));
        // P3 rows: {v3v0, v3v2, v3v3, 0}
        float P3 = row_sum_f(v3 * fmaf(q0, v0, fmaf(q1, v2v, q2 * v3)));
        float A10 = rl(P2, 0), A11 = rl(P2, 16) + DIAG5;
        float A21 = rl(P2, 32), A31 = rl(P2, 48);
        float A30 = rl(P3, 0), A32 = rl(P3, 16), A33 = rl(P3, 32) + DIAG5;

        // ---- reward: m'Qm + tr(Q*covc)/5 with Q=diag(1,1,10,1)
        v2f MM02 = { nmm0, nmm2 };
        v2f MM13 = { nmm1, nmm3 };
        v2f RW = MM02 * MM02;
        RW = MM13 * MM13 + RW;
        float rwm = fmaf(9.0f * nmm2, nmm2, RW.x + RW.y);
        float rwa = A00 + A11 + 10.0f * A22 + A33;
        acc -= fmaf(0.2f, rwa, rwm);

        // ---- remaining cholesky of 5*cov
        float nc10 = A10 * i0;
        float nc30 = A30 * i0;
        float b11 = fmaf(-nc10, nc10, A11);
        float i1 = __builtin_amdgcn_rsqf(b11);
        float nc11 = b11 * i1;
        float nc21 = fmaf(-nc20, nc10, A21) * i1;
        float nc31 = fmaf(-nc30, nc10, A31) * i1;
        float b22 = fmaf(-nc21, nc21, b22p);
        float i2 = __builtin_amdgcn_rsqf(b22);
        float nc22 = b22 * i2;
        float nc32 = fmaf(-nc31, nc21, fmaf(-nc30, nc20, A32)) * i2;
        float b33 = fmaf(-nc32, nc32, fmaf(-nc31, nc31, fmaf(-nc30, nc30, A33)));
        float nc33 = b33 * __builtin_amdgcn_rsqf(b33);

        c00 = nc00; c10 = nc10; c20 = nc20; c30 = nc30;
        c11 = nc11; c21 = nc21; c31 = nc31;
        c22 = nc22; c32 = nc32; c33 = nc33;
        mmf0 = nmm0; mmf1 = nmm1; mmf2 = nmm2; mmf3 = nmm3;
        frmf = nfrm;
    }

    if (l == 0) out[0] = acc;
}

extern "C" void kernel_launch(void* const* d_in, const int* in_sizes, int n_in,
                              void* d_out, int out_size, void* d_ws, size_t ws_size,
                              hipStream_t stream) {
    (void)in_sizes; (void)n_in; (void)out_size; (void)d_ws; (void)ws_size;
    const float* p = (const float*)d_in[0];
    float* out = (float*)d_out;
    hipLaunchKernelGGL(horizon_kernel, dim3(1), dim3(64), 0, stream, p, out);
}